// Round 1
// baseline (667.150 us; speedup 1.0000x reference)
//
#include <hip/hip_runtime.h>

// FastSurf fused kernel: trilinear grid gather + density MLP + view-embed + rgb MLP.
// f16 MFMA (16x16x32), weights-as-A persistent in registers, activations staged in LDS.

#define NPTS   (1 << 20)
#define NCHUNK (NPTS / 64)

typedef _Float16 half8  __attribute__((ext_vector_type(8)));
typedef _Float16 half4_t __attribute__((ext_vector_type(4)));
typedef float    f32x4  __attribute__((ext_vector_type(4)));

// ---- workspace layout (element offsets in halfs) ----
#define OFF_DW1T 0        // 128x32
#define OFF_DW2T 4096     // 128x128
#define OFF_RW1A 20480    // 128x32 (rgb layer1, feature part)
#define OFF_RW1B 24576    // 128x32 (rgb layer1, embed+ff part)
#define OFF_RW2T 28672    // 128x128
#define HALFS_TOTAL 45056
#define OFF_RW3T_BYTES (HALFS_TOTAL * 2)   // then 3x128 f32

#define HSTR 136   // h-buffer row stride (halfs); 272B = 17*16B -> aligned, ~2-way banks
#define FSTR 40    // feat/emb row stride (halfs); 80B = 5*16B

__global__ void prep_weights(const float* __restrict__ dW1,
                             const float* __restrict__ dW2,
                             const float* __restrict__ rW1,
                             const float* __restrict__ rW2,
                             const float* __restrict__ rW3,
                             _Float16* __restrict__ wsh,
                             float* __restrict__ rw3t)
{
    int tid = blockIdx.x * 256 + threadIdx.x;
    if (tid >= 16384) return;
    int n = tid >> 7, k = tid & 127;
    wsh[OFF_DW2T + n*128 + k] = (_Float16)dW2[k*128 + n];
    wsh[OFF_RW2T + n*128 + k] = (_Float16)rW2[k*128 + n];
    if (k < 32) {
        wsh[OFF_DW1T + n*32 + k] = (k < 12) ? (_Float16)dW1[k*128 + n] : (_Float16)0.f;
        wsh[OFF_RW1A + n*32 + k] = (k < 12) ? (_Float16)rW1[k*128 + n] : (_Float16)0.f;
        wsh[OFF_RW1B + n*32 + k] = (k < 29) ? (_Float16)rW1[(12 + k)*128 + n] : (_Float16)0.f;
    }
    if (k < 3) rw3t[k*128 + n] = rW3[n*3 + k];
}

__device__ __forceinline__ void store_act(_Float16* buf, int n, int ub,
                                          f32x4 acc, const float* __restrict__ bias)
{
    float4 b4 = *(const float4*)(bias + ub);
    half4_t v;
    v[0] = (_Float16)fmaxf(acc[0] + b4.x, 0.f);
    v[1] = (_Float16)fmaxf(acc[1] + b4.y, 0.f);
    v[2] = (_Float16)fmaxf(acc[2] + b4.z, 0.f);
    v[3] = (_Float16)fmaxf(acc[3] + b4.w, 0.f);
    *(half4_t*)(buf + n*HSTR + ub) = v;
}

#define MFMA(a, b, c) __builtin_amdgcn_mfma_f32_16x16x32_f16((a), (b), (c), 0, 0, 0)

__global__ __launch_bounds__(256) void fastsurf_main(
    const float* __restrict__ x, const float* __restrict__ grid,
    const float* __restrict__ db1, const float* __restrict__ db2,
    const float* __restrict__ dW3, const float* __restrict__ db3,
    const float* __restrict__ rb1, const float* __restrict__ rb2,
    const float* __restrict__ rb3,
    const _Float16* __restrict__ wsh, const float* __restrict__ rw3t,
    float* __restrict__ out)
{
    __shared__ _Float16 featA[64 * FSTR];
    __shared__ _Float16 embA [64 * FSTR];
    __shared__ _Float16 h1buf[64 * HSTR];
    __shared__ _Float16 h2buf[64 * HSTR];

    const int t  = threadIdx.x;
    const int wv = t >> 6;       // wave id 0..3 -> owns output units wv*32..wv*32+31
    const int l  = t & 63;
    const int ln = l & 15;       // m within rowtile (A) / n point within tile (B)
    const int qd = l >> 4;       // quad 0..3
    const int p  = t >> 2;       // gather: point 0..63
    const int q  = t & 3;        // gather: sub-thread 0..3
    const int u0 = (wv*2 + 0) * 16;
    const int u1 = (wv*2 + 1) * 16;

    // persistent K=128 layer weight fragments (A operand)
    half8 a_d2[2][4], a_r2[2][4];
#pragma unroll
    for (int rt = 0; rt < 2; ++rt) {
        const int m = (wv*2 + rt)*16 + ln;
#pragma unroll
        for (int ks = 0; ks < 4; ++ks) {
            a_d2[rt][ks] = *(const half8*)(wsh + OFF_DW2T + m*128 + ks*32 + qd*8);
            a_r2[rt][ks] = *(const half8*)(wsh + OFF_RW2T + m*128 + ks*32 + qd*8);
        }
    }

    for (int chunk = blockIdx.x; chunk < NCHUNK; chunk += gridDim.x) {
        const int pbase = chunk * 64;

        // ---------- phase 0: trilinear gather + view embedding ----------
        {
            const int P = pbase + p;
            const float4 xa = *(const float4*)(x + (size_t)P*8);
            const float4 xb = *(const float4*)(x + (size_t)P*8 + 4);
            float ux = fminf(fmaxf(xa.x, 0.f), 1.f) * 159.f;
            float uy = fminf(fmaxf(xa.y, 0.f), 1.f) * 159.f;
            float uz = fminf(fmaxf(xa.z, 0.f), 1.f) * 159.f;
            float fx = fminf(floorf(ux), 158.f);
            float fy = fminf(floorf(uy), 158.f);
            float fz = fminf(floorf(uz), 158.f);
            int ix = (int)fx, iy = (int)fy, iz = (int)fz;
            float wx = ux - fx, wy = uy - fy, wz = uz - fz;

            const int bx = q >> 1, by = q & 1;   // this thread: corners (bx,by,z0/z1)
            float wxy = (bx ? wx : 1.f - wx) * (by ? wy : 1.f - wy);
            float s0 = wxy * (1.f - wz), s1 = wxy * wz;
            const float* c = grid + (size_t)(((ix + bx)*160 + (iy + by))*160 + iz) * 12;
            float4 A0 = *(const float4*)(c);
            float4 A1 = *(const float4*)(c + 4);
            float4 A2 = *(const float4*)(c + 8);
            float4 B0 = *(const float4*)(c + 12);
            float4 B1 = *(const float4*)(c + 16);
            float4 B2 = *(const float4*)(c + 20);
            float f[12];
            f[0] = s0*A0.x + s1*B0.x;  f[1] = s0*A0.y + s1*B0.y;
            f[2] = s0*A0.z + s1*B0.z;  f[3] = s0*A0.w + s1*B0.w;
            f[4] = s0*A1.x + s1*B1.x;  f[5] = s0*A1.y + s1*B1.y;
            f[6] = s0*A1.z + s1*B1.z;  f[7] = s0*A1.w + s1*B1.w;
            f[8] = s0*A2.x + s1*B2.x;  f[9] = s0*A2.y + s1*B2.y;
            f[10]= s0*A2.z + s1*B2.z;  f[11]= s0*A2.w + s1*B2.w;
#pragma unroll
            for (int j = 0; j < 12; ++j) {
                f[j] += __shfl_xor(f[j], 1);
                f[j] += __shfl_xor(f[j], 2);
            }
            // featA row p: 32 halfs, ch>=12 zeroed
            half8 fv = { (_Float16)0.f,(_Float16)0.f,(_Float16)0.f,(_Float16)0.f,
                         (_Float16)0.f,(_Float16)0.f,(_Float16)0.f,(_Float16)0.f };
            if (q == 0) {
                fv[0]=(_Float16)f[0]; fv[1]=(_Float16)f[1]; fv[2]=(_Float16)f[2]; fv[3]=(_Float16)f[3];
                fv[4]=(_Float16)f[4]; fv[5]=(_Float16)f[5]; fv[6]=(_Float16)f[6]; fv[7]=(_Float16)f[7];
            } else if (q == 1) {
                fv[0]=(_Float16)f[8]; fv[1]=(_Float16)f[9]; fv[2]=(_Float16)f[10]; fv[3]=(_Float16)f[11];
            }
            *(half8*)(featA + p*FSTR + q*8) = fv;

            // embA row p: [vd(3), sin/cos f=1,2,4,8 (24), ff(2), 0 pad] = 32 halfs
            const float v0 = xb.y, v1 = xb.z, v2 = xb.w;
            const float ff0 = xa.w, ff1 = xb.x;
            half8 ev = { (_Float16)0.f,(_Float16)0.f,(_Float16)0.f,(_Float16)0.f,
                         (_Float16)0.f,(_Float16)0.f,(_Float16)0.f,(_Float16)0.f };
            if (q == 0) {
                ev[0]=(_Float16)v0; ev[1]=(_Float16)v1; ev[2]=(_Float16)v2;
                ev[3]=(_Float16)__sinf(v0); ev[4]=(_Float16)__sinf(v1); ev[5]=(_Float16)__sinf(v2);
                ev[6]=(_Float16)__cosf(v0); ev[7]=(_Float16)__cosf(v1);
            } else if (q == 1) {
                ev[0]=(_Float16)__cosf(v2);
                ev[1]=(_Float16)__sinf(2.f*v0); ev[2]=(_Float16)__sinf(2.f*v1); ev[3]=(_Float16)__sinf(2.f*v2);
                ev[4]=(_Float16)__cosf(2.f*v0); ev[5]=(_Float16)__cosf(2.f*v1); ev[6]=(_Float16)__cosf(2.f*v2);
                ev[7]=(_Float16)__sinf(4.f*v0);
            } else if (q == 2) {
                ev[0]=(_Float16)__sinf(4.f*v1); ev[1]=(_Float16)__sinf(4.f*v2);
                ev[2]=(_Float16)__cosf(4.f*v0); ev[3]=(_Float16)__cosf(4.f*v1); ev[4]=(_Float16)__cosf(4.f*v2);
                ev[5]=(_Float16)__sinf(8.f*v0); ev[6]=(_Float16)__sinf(8.f*v1); ev[7]=(_Float16)__sinf(8.f*v2);
            } else {
                ev[0]=(_Float16)__cosf(8.f*v0); ev[1]=(_Float16)__cosf(8.f*v1); ev[2]=(_Float16)__cosf(8.f*v2);
                ev[3]=(_Float16)ff0; ev[4]=(_Float16)ff1;
            }
            *(half8*)(embA + p*FSTR + q*8) = ev;
        }
        __syncthreads();

        // ---------- phase 1: density layer 1 (K=32 padded) ----------
        {
            const half8 a0 = *(const half8*)(wsh + OFF_DW1T + (u0 + ln)*32 + qd*8);
            const half8 a1 = *(const half8*)(wsh + OFF_DW1T + (u1 + ln)*32 + qd*8);
#pragma unroll
            for (int tl = 0; tl < 4; ++tl) {
                const int n = tl*16 + ln;
                half8 b = *(const half8*)(featA + n*FSTR + qd*8);
                f32x4 z = {0.f, 0.f, 0.f, 0.f};
                f32x4 acc0 = MFMA(a0, b, z);
                f32x4 acc1 = MFMA(a1, b, z);
                store_act(h1buf, n, u0 + qd*4, acc0, db1);
                store_act(h1buf, n, u1 + qd*4, acc1, db1);
            }
        }
        __syncthreads();

        // ---------- phase 2: density layer 2 (K=128) ----------
        {
#pragma unroll
            for (int tl = 0; tl < 4; ++tl) {
                const int n = tl*16 + ln;
                f32x4 acc0 = {0.f,0.f,0.f,0.f}, acc1 = {0.f,0.f,0.f,0.f};
#pragma unroll
                for (int ks = 0; ks < 4; ++ks) {
                    half8 b = *(const half8*)(h1buf + n*HSTR + ks*32 + qd*8);
                    acc0 = MFMA(a_d2[0][ks], b, acc0);
                    acc1 = MFMA(a_d2[1][ks], b, acc1);
                }
                store_act(h2buf, n, u0 + qd*4, acc0, db2);
                store_act(h2buf, n, u1 + qd*4, acc1, db2);
            }
        }
        __syncthreads();

        // ---------- phase 3: sdf = h2 . dW3 + db3 (vector dot) ----------
        float sdf;
        {
            float s = 0.f;
#pragma unroll
            for (int i = 0; i < 4; ++i) {
                const int kb = q*32 + i*8;
                half8 hv = *(const half8*)(h2buf + p*HSTR + kb);
                float4 wa = *(const float4*)(dW3 + kb);
                float4 wb = *(const float4*)(dW3 + kb + 4);
                s += (float)hv[0]*wa.x + (float)hv[1]*wa.y + (float)hv[2]*wa.z + (float)hv[3]*wa.w
                   + (float)hv[4]*wb.x + (float)hv[5]*wb.y + (float)hv[6]*wb.z + (float)hv[7]*wb.w;
            }
            s += __shfl_xor(s, 1);
            s += __shfl_xor(s, 2);
            sdf = s + db3[0];
        }

        // ---------- phase 4: rgb layer 1 (feat K=32 + emb K=32) ----------
        {
            const half8 aa0 = *(const half8*)(wsh + OFF_RW1A + (u0 + ln)*32 + qd*8);
            const half8 aa1 = *(const half8*)(wsh + OFF_RW1A + (u1 + ln)*32 + qd*8);
            const half8 ab0 = *(const half8*)(wsh + OFF_RW1B + (u0 + ln)*32 + qd*8);
            const half8 ab1 = *(const half8*)(wsh + OFF_RW1B + (u1 + ln)*32 + qd*8);
#pragma unroll
            for (int tl = 0; tl < 4; ++tl) {
                const int n = tl*16 + ln;
                half8 bf = *(const half8*)(featA + n*FSTR + qd*8);
                half8 be = *(const half8*)(embA  + n*FSTR + qd*8);
                f32x4 acc0 = {0.f,0.f,0.f,0.f}, acc1 = {0.f,0.f,0.f,0.f};
                acc0 = MFMA(aa0, bf, acc0);  acc0 = MFMA(ab0, be, acc0);
                acc1 = MFMA(aa1, bf, acc1);  acc1 = MFMA(ab1, be, acc1);
                store_act(h1buf, n, u0 + qd*4, acc0, rb1);
                store_act(h1buf, n, u1 + qd*4, acc1, rb1);
            }
        }
        __syncthreads();

        // ---------- phase 5: rgb layer 2 (K=128) ----------
        {
#pragma unroll
            for (int tl = 0; tl < 4; ++tl) {
                const int n = tl*16 + ln;
                f32x4 acc0 = {0.f,0.f,0.f,0.f}, acc1 = {0.f,0.f,0.f,0.f};
#pragma unroll
                for (int ks = 0; ks < 4; ++ks) {
                    half8 b = *(const half8*)(h1buf + n*HSTR + ks*32 + qd*8);
                    acc0 = MFMA(a_r2[0][ks], b, acc0);
                    acc1 = MFMA(a_r2[1][ks], b, acc1);
                }
                store_act(h2buf, n, u0 + qd*4, acc0, rb2);
                store_act(h2buf, n, u1 + qd*4, acc1, rb2);
            }
        }
        __syncthreads();

        // ---------- phase 6: rgb = h2 . rW3 + rb3, store [rgb, sdf] ----------
        {
            float r0 = 0.f, r1 = 0.f, r2 = 0.f;
#pragma unroll
            for (int i = 0; i < 4; ++i) {
                const int kb = q*32 + i*8;
                half8 hv = *(const half8*)(h2buf + p*HSTR + kb);
                float h0=hv[0], h1v=hv[1], h2v=hv[2], h3=hv[3], h4=hv[4], h5=hv[5], h6=hv[6], h7=hv[7];
                {
                    float4 wa = *(const float4*)(rw3t + kb);
                    float4 wb = *(const float4*)(rw3t + kb + 4);
                    r0 += h0*wa.x + h1v*wa.y + h2v*wa.z + h3*wa.w + h4*wb.x + h5*wb.y + h6*wb.z + h7*wb.w;
                }
                {
                    float4 wa = *(const float4*)(rw3t + 128 + kb);
                    float4 wb = *(const float4*)(rw3t + 128 + kb + 4);
                    r1 += h0*wa.x + h1v*wa.y + h2v*wa.z + h3*wa.w + h4*wb.x + h5*wb.y + h6*wb.z + h7*wb.w;
                }
                {
                    float4 wa = *(const float4*)(rw3t + 256 + kb);
                    float4 wb = *(const float4*)(rw3t + 256 + kb + 4);
                    r2 += h0*wa.x + h1v*wa.y + h2v*wa.z + h3*wa.w + h4*wb.x + h5*wb.y + h6*wb.z + h7*wb.w;
                }
            }
            r0 += __shfl_xor(r0, 1);  r0 += __shfl_xor(r0, 2);
            r1 += __shfl_xor(r1, 1);  r1 += __shfl_xor(r1, 2);
            r2 += __shfl_xor(r2, 1);  r2 += __shfl_xor(r2, 2);
            if (q == 0) {
                float4 o;
                o.x = r0 + rb3[0];
                o.y = r1 + rb3[1];
                o.z = r2 + rb3[2];
                o.w = sdf;
                *(float4*)(out + (size_t)(pbase + p)*4) = o;
            }
        }
        __syncthreads();
    }
}

extern "C" void kernel_launch(void* const* d_in, const int* in_sizes, int n_in,
                              void* d_out, int out_size, void* d_ws, size_t ws_size,
                              hipStream_t stream) {
    const float* x    = (const float*)d_in[0];
    const float* grid = (const float*)d_in[1];
    const float* dW1  = (const float*)d_in[2];
    const float* db1  = (const float*)d_in[3];
    const float* dW2  = (const float*)d_in[4];
    const float* db2  = (const float*)d_in[5];
    const float* dW3  = (const float*)d_in[6];
    const float* db3  = (const float*)d_in[7];
    const float* rW1  = (const float*)d_in[8];
    const float* rb1  = (const float*)d_in[9];
    const float* rW2  = (const float*)d_in[10];
    const float* rb2  = (const float*)d_in[11];
    const float* rW3  = (const float*)d_in[12];
    const float* rb3  = (const float*)d_in[13];
    float* out = (float*)d_out;

    _Float16* wsh = (_Float16*)d_ws;
    float* rw3t = (float*)((char*)d_ws + OFF_RW3T_BYTES);

    prep_weights<<<64, 256, 0, stream>>>(dW1, dW2, rW1, rW2, rW3, wsh, rw3t);
    fastsurf_main<<<1024, 256, 0, stream>>>(x, grid, db1, db2, dW3, db3,
                                            rb1, rb2, rb3, wsh, rw3t, out);
}